// Round 9
// baseline (209.593 us; speedup 1.0000x reference)
//
#include <hip/hip_runtime.h>
#include <math.h>

// ---------------- problem constants ----------------
#define N        2048
#define NT       256      // threads per block
#define NSC      81       // number of scales (J+1)
#define BATCH    64
#define WS_WIN   94       // sliding window = 32*3-2
#define NOUT     1955     // N - WS_WIN + 1
#define DT_S     0.1f
#define W0_C     6.0f
#define PI_F     3.14159265358979f
#define TWOPI_F  6.28318530717959f
#define PIM14    0.7511255444649425f   // pi^(-1/4)
#define C_SQ2H   0.70710678118654752f  // sqrt(2)/2

// pad-swizzle: +1 element every 16. All stage addresses are hand-decomposed
// into per-thread base + compile-time offsets (exact, verified: no carries
// cross the >>4 boundary for these strides).
#define LDSN     2176     // 2048 + 128 pad elements

// packed 2xfp32 complex: backend emits v_pk_add_f32 / v_pk_mul_f32 / v_pk_fma_f32
typedef float v2f __attribute__((ext_vector_type(2)));

__device__ __forceinline__ v2f shuf10(v2f a) { return __builtin_shufflevector(a, a, 1, 0); }
__device__ __forceinline__ v2f splat0(v2f a) { return __builtin_shufflevector(a, a, 0, 0); }
__device__ __forceinline__ v2f splat1(v2f a) { return __builtin_shufflevector(a, a, 1, 1); }

// complex multiply — 3 pk ops
__device__ __forceinline__ v2f cmul(v2f a, v2f b) {
    const v2f sgn = {-1.f, 1.f};
    return splat0(a) * b + sgn * (splat1(a) * shuf10(b));
}

// multiply by s*i (s=SGN)
template<int SGN>
__device__ __forceinline__ v2f muli(v2f a) {
    const v2f sgn = {-(float)SGN, (float)SGN};
    return sgn * shuf10(a);
}

// 8-point DFT, natural-order outputs. ZT: x[4..7] are structurally zero
// (CWT ifft input: Morlet filter kills k=0 and k>=N/2 -> upper half zero).
template<int SGN, bool ZT>
__device__ __forceinline__ void dft8(const v2f (&x)[8], v2f (&y)[8]) {
    v2f t0, t1, t2, t3, u0, d1, d2, d3;
    if (ZT) {
        t0 = x[0]; t1 = x[1]; t2 = x[2]; t3 = x[3];
        u0 = x[0]; d1 = x[1]; d2 = x[2]; d3 = x[3];
    } else {
        t0 = x[0] + x[4]; t1 = x[1] + x[5]; t2 = x[2] + x[6]; t3 = x[3] + x[7];
        u0 = x[0] - x[4]; d1 = x[1] - x[5]; d2 = x[2] - x[6]; d3 = x[3] - x[7];
    }
    v2f u1 = C_SQ2H * (d1 + muli<SGN>(d1));
    v2f u2 = muli<SGN>(d2);
    v2f u3 = C_SQ2H * (muli<SGN>(d3) - d3);
    v2f a0 = t0 + t2, a1 = t1 + t3, b0 = t0 - t2, b1 = muli<SGN>(t1 - t3);
    y[0] = a0 + a1; y[4] = a0 - a1; y[2] = b0 + b1; y[6] = b0 - b1;
    v2f c0 = u0 + u2, c1 = u1 + u3, g0 = u0 - u2, g1 = muli<SGN>(u1 - u3);
    y[1] = c0 + c1; y[5] = c0 - c1; y[3] = g0 + g1; y[7] = g0 - g1;
}

// twiddle powers w^1..w^7, w = exp(SGN*2pi*i*jm/N)
template<int SGN>
__device__ __forceinline__ void twiddles(int jm, v2f (&w)[8]) {
    float ang = (float)SGN * (TWOPI_F / (float)N) * (float)jm;
    float sn, cs; __sincosf(ang, &sn, &cs);
    w[1] = (v2f){cs, sn};
    w[2] = cmul(w[1], w[1]);
    w[3] = cmul(w[2], w[1]);
    w[4] = cmul(w[2], w[2]);
    w[5] = cmul(w[3], w[2]);
    w[6] = cmul(w[3], w[3]);
    w[7] = cmul(w[4], w[3]);
}

// ---------------- single-buffer in-place Stockham FFT ----------------
// Each stage: read all inputs -> barrier -> write all outputs -> barrier.
// One LDS buffer total (vs ping-pong pair) -> 33792 B/block -> 4 blocks/CU.
// Register in / register out: x[i] = element tid + i*256, natural order.
// SGN=-1: forward (numpy fft). SGN=+1: inverse exponent (1/N not applied).
template<int SGN, bool ZT>
__device__ __forceinline__ void fft2048_ip(v2f (&x)[8], v2f* __restrict__ L, int tid) {
    const int rb = tid + (tid >> 4);         // SWZ(tid)

    __syncthreads();                          // L free (prior readers done)

    // ---- stage 1 (m=1): regs -> L.  SWZ(8tid+u) = 8tid+(tid>>1)+u (exact)
    {
        v2f y[8];
        dft8<SGN, ZT>(x, y);
        v2f w[8];
        twiddles<SGN>(tid, w);
        const int wb = 8 * tid + (tid >> 1);
        L[wb]     = y[0];
        L[wb + 1] = cmul(y[1], w[1]);
        L[wb + 2] = cmul(y[2], w[2]);
        L[wb + 3] = cmul(y[3], w[3]);
        L[wb + 4] = cmul(y[4], w[4]);
        L[wb + 5] = cmul(y[5], w[5]);
        L[wb + 6] = cmul(y[6], w[6]);
        L[wb + 7] = cmul(y[7], w[7]);
    }
    __syncthreads();

    // ---- stage m=8: in-place. reads SWZ(tid+256p) = rb+272p;
    // writes SWZ(64j+k+8u) = (68j+k) + {0,8,17,25,34,42,51,59}[u]
    {
        v2f xin[8];
        #pragma unroll
        for (int p = 0; p < 8; ++p) xin[p] = L[rb + 272 * p];
        __syncthreads();                      // all reads done before writes
        v2f y[8];
        dft8<SGN, false>(xin, y);
        const int j = tid >> 3, k = tid & 7;
        v2f w[8];
        twiddles<SGN>(8 * j, w);
        const int wb = 68 * j + k;
        L[wb]      = y[0];
        L[wb + 8]  = cmul(y[1], w[1]);
        L[wb + 17] = cmul(y[2], w[2]);
        L[wb + 25] = cmul(y[3], w[3]);
        L[wb + 34] = cmul(y[4], w[4]);
        L[wb + 42] = cmul(y[5], w[5]);
        L[wb + 51] = cmul(y[6], w[6]);
        L[wb + 59] = cmul(y[7], w[7]);
    }
    __syncthreads();

    // ---- stage m=64: in-place. reads rb+272p; writes SWZ(base)+68u,
    // base = tid + 448*(tid>>6)
    {
        v2f xin[8];
        #pragma unroll
        for (int p = 0; p < 8; ++p) xin[p] = L[rb + 272 * p];
        __syncthreads();
        v2f y[8];
        dft8<SGN, false>(xin, y);
        const int j = tid >> 6;
        v2f w[8];
        twiddles<SGN>(64 * j, w);
        const int base = tid + 448 * j;
        const int wb   = base + (base >> 4);
        L[wb]          = y[0];
        L[wb + 68]     = cmul(y[1], w[1]);
        L[wb + 2 * 68] = cmul(y[2], w[2]);
        L[wb + 3 * 68] = cmul(y[3], w[3]);
        L[wb + 4 * 68] = cmul(y[4], w[4]);
        L[wb + 5 * 68] = cmul(y[5], w[5]);
        L[wb + 6 * 68] = cmul(y[6], w[6]);
        L[wb + 7 * 68] = cmul(y[7], w[7]);
    }
    __syncthreads();

    // ---- final radix-4 (m=512, j=0, no twiddles): L -> regs.
    // reads SWZ(q+512p) = SWZ(q)+544p; x[2u+qq] = element tid+(2u+qq)*256
    #pragma unroll
    for (int qq = 0; qq < 2; ++qq) {
        const int q   = tid + qq * 256;
        const int rb4 = q + (q >> 4);
        v2f x0 = L[rb4];
        v2f x1 = L[rb4 + 544];
        v2f x2 = L[rb4 + 2 * 544];
        v2f x3 = L[rb4 + 3 * 544];
        v2f a0 = x0 + x2, a1 = x1 + x3;
        v2f b0 = x0 - x2, b1 = muli<SGN>(x1 - x3);
        x[0 + qq] = a0 + a1;
        x[2 + qq] = b0 + b1;
        x[4 + qq] = a0 - a1;
        x[6 + qq] = b0 - b1;
    }
    // no trailing barrier: next FFT's entry barrier protects L
}

// ---------------- K1: normalize + forward FFT of each signal ----------------
__global__ __launch_bounds__(NT) void k_fft_in(const float* __restrict__ x,
                                               v2f* __restrict__ spec) {
    __shared__ v2f  L[LDSN];
    __shared__ float rs[NT], rq[NT];
    const int    tid = threadIdx.x;
    const float* y   = x + (size_t)blockIdx.x * N;

    float v[8];
    float lsum = 0.f, lsq = 0.f;
    #pragma unroll
    for (int i = 0; i < 8; ++i) {
        float t = y[tid + i * NT];
        v[i] = t; lsum += t; lsq += t * t;
    }
    rs[tid] = lsum; rq[tid] = lsq;
    __syncthreads();
    for (int o = NT / 2; o > 0; o >>= 1) {
        if (tid < o) { rs[tid] += rs[tid + o]; rq[tid] += rq[tid + o]; }
        __syncthreads();
    }
    const float mean = rs[0] * (1.f / N);
    const float var  = rq[0] * (1.f / N) - mean * mean;
    const float inv  = rsqrtf(var);

    v2f z[8];
    #pragma unroll
    for (int i = 0; i < 8; ++i) z[i] = (v2f){(v[i] - mean) * inv, 0.f};

    fft2048_ip<-1, false>(z, L, tid);

    v2f* o2 = spec + (size_t)blockIdx.x * N;
    #pragma unroll
    for (int i = 0; i < 8; ++i) o2[tid + i * NT] = z[i];
}

// ---------------- K2: per (batch, scale) CWT + smoothing ----------------
// Single FFT buffer L (in-place stages) + park stash S: 17408+16384 = 33792 B
// -> 4 blocks/CU (was 3 at 51200). Allocator-proof: nothing held in registers
// across an FFT call; the surviving array is parked in S at thread-owned idx.
__global__ __launch_bounds__(NT) void k_wct(const v2f* __restrict__ spec,
                                            v2f* __restrict__ Tp,
                                            v2f* __restrict__ Tc, int b0) {
    __shared__ v2f L[LDSN];
    __shared__ v2f S[N];             // park stash, thread-owned access only
    const int tid  = threadIdx.x;
    const int sidx = blockIdx.x % NSC;
    const int bl   = blockIdx.x / NSC;
    const int b    = b0 + bl;

    const float s0    = 2.f * DT_S * (W0_C + sqrtf(2.f + W0_C * W0_C)) / (4.f * PI_F);
    const float s     = s0 * exp2f(0.125f * (float)sidx);
    const float inv_s = 1.f / s;

    const v2f* yh1 = spec + (size_t)(b * 2 + 0) * N;
    const v2f* yh2 = spec + (size_t)(b * 2 + 1) * N;

    // Morlet filter (w>0 one-sided), unit-energy norm, ifft 1/N folded in
    const float nrm   = PIM14 * sqrtf(TWOPI_F * s / DT_S) * (1.f / N);
    const float wstep = TWOPI_F / ((float)N * DT_S);

    // ---- W1 = ifft(filter * yh1), then park in S ----
    {
        v2f w[8];
        #pragma unroll
        for (int i = 0; i < 8; ++i) {
            int   k = tid + i * NT;
            float f = 0.f;
            if (k >= 1 && k < N / 2) {
                float arg = s * (wstep * (float)k) - W0_C;
                f = nrm * expf(-0.5f * arg * arg);
            }
            w[i] = yh1[k] * f;
        }
        fft2048_ip<+1, true>(w, L, tid);     // upper half of input is zero
        #pragma unroll
        for (int i = 0; i < 8; ++i) S[tid + i * NT] = w[i];   // park
    }

    // ---- W2 = ifft(filter * yh2) ----
    v2f w2[8];
    #pragma unroll
    for (int i = 0; i < 8; ++i) {
        int   k = tid + i * NT;
        float f = 0.f;                  // recompute filter (keeps live set small)
        if (k >= 1 && k < N / 2) {
            float arg = s * (wstep * (float)k) - W0_C;
            f = nrm * expf(-0.5f * arg * arg);
        }
        w2[i] = yh2[k] * f;
    }
    fft2048_ip<+1, true>(w2, L, tid);

    // ---- products; P stays in regs, C parked in S (overwrites W1 slots) ----
    v2f P[8];
    #pragma unroll
    for (int i = 0; i < 8; ++i) {
        v2f a = S[tid + i * NT];         // unpark W1
        v2f c = w2[i];
        P[i] = (v2f){(a.x * a.x + a.y * a.y) * inv_s,
                     (c.x * c.x + c.y * c.y) * inv_s};
        S[tid + i * NT] = (v2f){(a.x * c.x + a.y * c.y) * inv_s,
                                (a.y * c.x - a.x * c.y) * inv_s};  // park C
    }

    // Gaussian time-smoothing in Fourier domain (1/N folded into F)
    const float sdt = s / DT_S;
    const float fc  = -0.5f * sdt * sdt * (TWOPI_F / (float)N) * (TWOPI_F / (float)N);

    // --- P chain: fft -> filter -> ifft -> store ---
    fft2048_ip<-1, false>(P, L, tid);
    #pragma unroll
    for (int i = 0; i < 8; ++i) {
        int   k  = tid + i * NT;
        int   mk = min(k, N - k);
        float F  = expf(fc * (float)(mk * mk)) * (1.f / N);
        P[i] *= F;
    }
    fft2048_ip<+1, false>(P, L, tid);

    v2f* Tpo = Tp + ((size_t)bl * NSC + sidx) * N;
    #pragma unroll
    for (int i = 0; i < 8; ++i) Tpo[tid + i * NT] = P[i];

    // --- C chain: unpark, fft -> filter -> ifft -> store ---
    v2f C[8];
    #pragma unroll
    for (int i = 0; i < 8; ++i) C[i] = S[tid + i * NT];       // unpark C

    fft2048_ip<-1, false>(C, L, tid);
    #pragma unroll
    for (int i = 0; i < 8; ++i) {
        int   k  = tid + i * NT;
        int   mk = min(k, N - k);
        float F  = expf(fc * (float)(mk * mk)) * (1.f / N);
        C[i] *= F;
    }
    fft2048_ip<+1, false>(C, L, tid);

    v2f* Tco = Tc + ((size_t)bl * NSC + sidx) * N;
    #pragma unroll
    for (int i = 0; i < 8; ++i) Tco[tid + i * NT] = C[i];
}

// ---------------- K3: scale-axis boxcar conv + coherence + scale sum --------
__global__ __launch_bounds__(NT) void k_coh(const v2f* __restrict__ Tp,
                                            const v2f* __restrict__ Tc,
                                            float* __restrict__ coh, int b0) {
    const int bl = blockIdx.x >> 3;
    const int t  = ((blockIdx.x & 7) << 8) + threadIdx.x;
    const int b  = b0 + bl;
    const v2f* colp = Tp + (size_t)bl * NSC * N + t;
    const v2f* colc = Tc + (size_t)bl * NSC * N + t;

    v2f qp[10], qc[10];
    #pragma unroll
    for (int i = 0; i < 10; ++i) { qp[i] = (v2f){0.f, 0.f}; qc[i] = (v2f){0.f, 0.f}; }
    #pragma unroll
    for (int i = 0; i < 5; ++i) {
        qp[5 + i] = colp[(size_t)i * N];
        qc[5 + i] = colc[(size_t)i * N];
    }

    float acc = 0.f;
    const float w9 = 1.f / 9.f;
    for (int i = 0; i < NSC; ++i) {
        v2f sp = qp[0], sc = qc[0];
        #pragma unroll
        for (int k = 1; k < 10; ++k) { sp += qp[k]; sc += qc[k]; }
        v2f sv = (sp - 0.5f * (qp[0] + qp[9])) * w9;   // (S1, S2)
        v2f cv = (sc - 0.5f * (qc[0] + qc[9])) * w9;   // (S12.re, S12.im)
        acc += (cv.x * cv.x + cv.y * cv.y) / (sv.x * sv.y);
        #pragma unroll
        for (int k = 0; k < 9; ++k) { qp[k] = qp[k + 1]; qc[k] = qc[k + 1]; }
        int c = i + 5;
        if (c < NSC) {
            qp[9] = colp[(size_t)c * N];
            qc[9] = colc[(size_t)c * N];
        } else {
            qp[9] = (v2f){0.f, 0.f};
            qc[9] = (v2f){0.f, 0.f};
        }
    }
    coh[(size_t)b * N + t] = acc;
}

// ---------------- K4: sliding-window sum over time ----------------
__global__ __launch_bounds__(NT) void k_win(const float* __restrict__ coh,
                                            float* __restrict__ out) {
    __shared__ float row[N];
    const int b   = blockIdx.x;
    const int tid = threadIdx.x;
    for (int i = tid; i < N; i += NT) row[i] = coh[(size_t)b * N + i];
    __syncthreads();
    for (int t0 = tid; t0 < NOUT; t0 += NT) {
        float ssum = 0.f;
        for (int k = 0; k < WS_WIN; ++k) ssum += row[t0 + k];
        out[(size_t)b * NOUT + t0] = ssum;
    }
}

// ---------------- host launcher ----------------
extern "C" void kernel_launch(void* const* d_in, const int* in_sizes, int n_in,
                              void* d_out, int out_size, void* d_ws, size_t ws_size,
                              hipStream_t stream) {
    const float* x   = (const float*)d_in[0];
    float*       out = (float*)d_out;
    char*        ws  = (char*)d_ws;

    const size_t spec_bytes = (size_t)BATCH * 2 * N * sizeof(v2f);  // 2 MB
    const size_t coh_bytes  = (size_t)BATCH * N * sizeof(float);    // 512 KB
    const size_t perBatchT  = (size_t)NSC * N * 2 * sizeof(v2f);    // Tp+Tc per batch

    v2f*   spec  = (v2f*)ws;
    float* coh   = (float*)(ws + spec_bytes);
    char*  Tbase = ws + spec_bytes + coh_bytes;

    size_t avail = (ws_size > spec_bytes + coh_bytes) ? (ws_size - spec_bytes - coh_bytes) : 0;
    int chunk = (int)(avail / perBatchT);
    if (chunk < 1) chunk = 1;
    if (chunk > BATCH) chunk = BATCH;

    // planar layout: Tp plane then Tc plane, each chunk*NSC*N v2f
    v2f* Tp = (v2f*)Tbase;
    v2f* Tc = Tp + (size_t)chunk * NSC * N;

    k_fft_in<<<BATCH * 2, NT, 0, stream>>>(x, spec);
    for (int b0 = 0; b0 < BATCH; b0 += chunk) {
        int cb = BATCH - b0 < chunk ? BATCH - b0 : chunk;
        k_wct<<<cb * NSC, NT, 0, stream>>>(spec, Tp, Tc, b0);
        k_coh<<<cb * 8, NT, 0, stream>>>(Tp, Tc, coh, b0);
    }
    k_win<<<BATCH, NT, 0, stream>>>(coh, out);
}